// Round 13
// baseline (793.566 us; speedup 1.0000x reference)
//
#include <hip/hip_runtime.h>

#define VIN  16000
#define V1q  16384
#define V2q  4096
#define Kq   16
#define FCIN 65536

typedef unsigned short u16;
typedef unsigned int u32;
typedef __attribute__((ext_vector_type(8))) short short8;
typedef __attribute__((ext_vector_type(4))) float f32x4;
typedef __attribute__((ext_vector_type(4))) u32 u32x4;

__device__ __forceinline__ float bf2f(u16 v) { return __uint_as_float((unsigned)v << 16); }
__device__ __forceinline__ float bflo(u32 u) { return __uint_as_float(u << 16); }
__device__ __forceinline__ float bfhi(u32 u) { return __uint_as_float(u & 0xffff0000u); }
__device__ __forceinline__ u16 f2bf(float f) {
    unsigned u = __float_as_uint(f);
    return (u16)((u + 0x7fffu + ((u >> 16) & 1u)) >> 16);
}
__device__ __forceinline__ u32 packbf(float a, float b) {
    return (u32)f2bf(a) | ((u32)f2bf(b) << 16);
}

// ---- barrier state per chain (ints): XT[xcd]=xcd*32, ARR=256, FLG=288,
//      LVL[(k-1)*8+xcd]=320+(..)*32 ; chain stride 8192 ----
__global__ void zero_bar(int* __restrict__ bar) {
    bar[blockIdx.x * 256 + threadIdx.x] = 0;   // 64 blocks -> 16384 ints
}

// ---------------- workspace zero (X0 level incl. pad rows) ----------------
__global__ void zero_ws(u16* __restrict__ X0) {
    size_t idx = (size_t)blockIdx.x * 256 + threadIdx.x;   // 2048*256
    float4 z = {0.f, 0.f, 0.f, 0.f};
    *(float4*)(X0 + idx * 8) = z;
}

// ---------------- BatchNorm stats (two stage) ----------------
__global__ void bn_part(const float* __restrict__ x, float* __restrict__ part) {
    int c  = blockIdx.y;
    int bx = blockIdx.x;
    int b  = bx >> 2;
    int vc = bx & 3;
    const float* p = x + (size_t)(b * 16 + c) * VIN + vc * 4000;
    float s = 0.f, s2 = 0.f;
    for (int v = threadIdx.x; v < 4000; v += 256) {
        float val = p[v];
        s += val; s2 += val * val;
    }
    for (int o = 32; o; o >>= 1) { s += __shfl_down(s, o); s2 += __shfl_down(s2, o); }
    __shared__ float ls[4], ls2[4];
    int wid = threadIdx.x >> 6;
    if ((threadIdx.x & 63) == 0) { ls[wid] = s; ls2[wid] = s2; }
    __syncthreads();
    if (threadIdx.x == 0) {
        s = ls[0] + ls[1] + ls[2] + ls[3];
        s2 = ls2[0] + ls2[1] + ls2[2] + ls2[3];
        part[(c * 64 + bx) * 2]     = s;
        part[(c * 64 + bx) * 2 + 1] = s2;
    }
}

__global__ void bn_final(const float* __restrict__ part, float* __restrict__ mean_rstd) {
    int t = threadIdx.x;
    int c = t >> 4, j = t & 15;
    float s = 0.f, s2 = 0.f;
    for (int i = 0; i < 4; i++) {
        s  += part[(c * 64 + j * 4 + i) * 2];
        s2 += part[(c * 64 + j * 4 + i) * 2 + 1];
    }
    for (int o = 8; o; o >>= 1) { s += __shfl_down(s, o, 16); s2 += __shfl_down(s2, o, 16); }
    if (j == 0) {
        float m  = s / 256000.f;
        float var = s2 / 256000.f - m * m;
        mean_rstd[c]      = m;
        mean_rstd[16 + c] = rsqrtf(var + 1e-5f);
    }
}

// ---------------- inverse permutation, u16 index pack, bf16 vals pack ----------------
__global__ void build_iperm(const int* __restrict__ perm, int* __restrict__ iperm) {
    int v = blockIdx.x * 256 + threadIdx.x;
    if (v < V1q) iperm[perm[v]] = v;
}
__global__ void build_idx16(const int* __restrict__ c, u16* __restrict__ o, int n) {
    int i = blockIdx.x * 256 + threadIdx.x;
    if (i < n) o[i] = (u16)c[i];
}
__global__ void pack_vals(const float* __restrict__ v, u16* __restrict__ o, int n) {
    int i = blockIdx.x * 256 + threadIdx.x;
    if (i < n) o[i] = f2bf(v[i]);
}

// ------- normalize + transpose + permute scatter, bf16, PANEL-major fragment order -------
// dest col d -> panel d>>5, offset d&31: X0[(panel*V1 + v)*32 + (d&31)]
__global__ void norm_transpose_scatter(const float* __restrict__ x,
                                       const float* __restrict__ mean_rstd,
                                       const int* __restrict__ iperm,
                                       u16* __restrict__ X0) {
    __shared__ u16 tile[256][33];
    int u0 = blockIdx.x * 32;
    int t  = threadIdx.x;
    int jj = t & 31, half = t >> 5;
    for (int rr = 0; rr < 32; rr++) {
        int s = rr * 8 + half;           // source row = b*16 + c
        int c = s & 15, b = s >> 4;
        float val = x[(size_t)s * VIN + u0 + jj];
        val = (val - mean_rstd[c]) * mean_rstd[16 + c];
        int d = ((c >> 3) << 7) | (b << 3) | (c & 7);
        tile[d][jj] = f2bf(val);
    }
    __syncthreads();
    size_t pbase = (size_t)(t >> 5) * V1q * 32 + (t & 31);
    for (int j = 0; j < 32; j++) {
        int tv = iperm[u0 + j];
        X0[pbase + (size_t)tv * 32] = tile[t][j];
    }
}

// ---------------- weight packing into MFMA B-fragment order ----------------
__global__ void pack_w1(const float* __restrict__ w1, u16* __restrict__ B1p) {
    int i = blockIdx.x * 256 + threadIdx.x;   // 8192
    int j = i & 7, l = (i >> 3) & 63, nf = (i >> 9) & 1, s = i >> 10;
    int q = l >> 4;
    int k = s * 2 + (q >> 1);
    int c = (q & 1) * 8 + j;
    int f = nf * 16 + (l & 15);
    B1p[i] = f2bf(w1[f * 256 + c * 16 + k]);
}
__global__ void pack_w2(const float* __restrict__ w2, u16* __restrict__ B2p) {
    int i = blockIdx.x * 256 + threadIdx.x;   // 32768
    int j = i & 7, l = (i >> 3) & 63, nf = (i >> 9) & 3, k = i >> 11;
    int f1 = (l >> 4) * 8 + j;
    int f2 = nf * 16 + (l & 15);
    B2p[i] = f2bf(w2[f2 * 512 + f1 * 16 + k]);
}

// ------- pack P2f fp32 -> bf16 A-fragment order for FC MFMA -------
__global__ void pack_p(const float* __restrict__ P2f, u16* __restrict__ Pp) {
    int i = blockIdx.x * 256 + threadIdx.x;   // 131072
    int l = i & 63, ks = i >> 6;
    int b = l & 15, q = l >> 4;
    const float* src = P2f + (size_t)b * FCIN + ks * 32 + q * 8;
    float4 a0 = *(const float4*)(src);
    float4 a1 = *(const float4*)(src + 4);
    short8 v;
    v[0] = (short)f2bf(a0.x); v[1] = (short)f2bf(a0.y);
    v[2] = (short)f2bf(a0.z); v[3] = (short)f2bf(a0.w);
    v[4] = (short)f2bf(a1.x); v[5] = (short)f2bf(a1.y);
    v[6] = (short)f2bf(a1.z); v[7] = (short)f2bf(a1.w);
    *(short8*)(Pp + (size_t)i * 8) = v;
}

// ---------------- persistent panel-local Chebyshev chain ----------------
// Data: XS[k][panel 8][V][PW]. Panel = physical XCD (XCC_ID): the whole 15-level
// chain for a panel runs inside one L2 -> no fences, XCD-local barriers only.
// PWL: log2 panel width (5: conv1, 6: conv2). TPR = PW/8 threads per row.
template<int V, int PWL>
__launch_bounds__(256, 4)
__global__ void cheb_panel(const u16* __restrict__ idx16, const u16* __restrict__ valsb,
                           u16* __restrict__ XS, int* __restrict__ bar) {
    constexpr int PW  = 1 << PWL;
    constexpr int TPRL = PWL - 3;          // 8 elems (16B) per thread
    constexpr int TPR = 1 << TPRL;
    constexpr int RPP = 256 >> TPRL;       // rows per pass
    int t = threadIdx.x;
    int xcd;
    asm("s_getreg_b32 %0, hwreg(HW_REG_XCC_ID)" : "=s"(xcd));
    xcd &= 7;
    int nwg = gridDim.x;
    __shared__ int s_tick, s_cnt;
    if (t == 0) {
        s_tick = __hip_atomic_fetch_add(&bar[xcd * 32], 1, __ATOMIC_RELAXED, __HIP_MEMORY_SCOPE_AGENT);
        int a = __hip_atomic_fetch_add(&bar[256], 1, __ATOMIC_ACQ_REL, __HIP_MEMORY_SCOPE_AGENT);
        if (a == nwg - 1) {
            __hip_atomic_store(&bar[288], 1, __ATOMIC_RELEASE, __HIP_MEMORY_SCOPE_AGENT);
        } else {
            while (__hip_atomic_load(&bar[288], __ATOMIC_ACQUIRE, __HIP_MEMORY_SCOPE_AGENT) == 0)
                __builtin_amdgcn_s_sleep(8);
        }
        s_cnt = __hip_atomic_load(&bar[xcd * 32], __ATOMIC_RELAXED, __HIP_MEMORY_SCOPE_AGENT);
    }
    __syncthreads();
    int tick = s_tick, cnt = s_cnt;
    int chunk = (V + cnt - 1) / cnt;
    int r0 = tick * chunk;
    int r1 = r0 + chunk; if (r1 > V) r1 = V;
    const size_t S = (size_t)V * (8 * PW);          // level stride (elements)
    const size_t pbase = (size_t)xcd * V * PW;      // panel base within level
    int coff = (t & (TPR - 1)) * 8;                 // element offset in panel row

    for (int k = 1; k < 16; k++) {
        const u16* prev  = XS + (size_t)(k - 1) * S + pbase;
        const u16* prev2 = XS + (size_t)(k - 2) * S + pbase;
        u16* outp = XS + (size_t)k * S + pbase;
        float scale = (k == 1) ? 1.f : 2.f;
        int sub = (k >= 2);
        for (int r = r0 + (t >> TPRL); r < r1; r += RPP) {
            u32x4 iwa = *(const u32x4*)(idx16 + (size_t)r * 16);
            u32x4 iwb = *(const u32x4*)(idx16 + (size_t)r * 16 + 8);
            u32 wi[16] = {iwa.x & 0xffffu, iwa.x >> 16, iwa.y & 0xffffu, iwa.y >> 16,
                          iwa.z & 0xffffu, iwa.z >> 16, iwa.w & 0xffffu, iwa.w >> 16,
                          iwb.x & 0xffffu, iwb.x >> 16, iwb.y & 0xffffu, iwb.y >> 16,
                          iwb.z & 0xffffu, iwb.z >> 16, iwb.w & 0xffffu, iwb.w >> 16};
            u32x4 vwa = *(const u32x4*)(valsb + (size_t)r * 16);
            u32x4 vwb = *(const u32x4*)(valsb + (size_t)r * 16 + 8);
            u32 vw[8] = {vwa.x, vwa.y, vwa.z, vwa.w, vwb.x, vwb.y, vwb.z, vwb.w};
            // all 16 gathers issued before FMAs (MLP)
            u32x4 g[16];
#pragma unroll
            for (int j = 0; j < 16; j++)
                g[j] = *(const u32x4*)(prev + (size_t)wi[j] * PW + coff);
            float a[8] = {0.f, 0.f, 0.f, 0.f, 0.f, 0.f, 0.f, 0.f};
#pragma unroll
            for (int j = 0; j < 16; j++) {
                float v = (j & 1) ? bfhi(vw[j >> 1]) : bflo(vw[j >> 1]);
                a[0] += v * bflo(g[j].x); a[1] += v * bfhi(g[j].x);
                a[2] += v * bflo(g[j].y); a[3] += v * bfhi(g[j].y);
                a[4] += v * bflo(g[j].z); a[5] += v * bfhi(g[j].z);
                a[6] += v * bflo(g[j].w); a[7] += v * bfhi(g[j].w);
            }
            size_t ob = (size_t)r * PW + coff;
            float o[8];
            if (sub) {
                u32x4 p2 = *(const u32x4*)(prev2 + ob);
                o[0] = scale * a[0] - bflo(p2.x); o[1] = scale * a[1] - bfhi(p2.x);
                o[2] = scale * a[2] - bflo(p2.y); o[3] = scale * a[3] - bfhi(p2.y);
                o[4] = scale * a[4] - bflo(p2.z); o[5] = scale * a[5] - bfhi(p2.z);
                o[6] = scale * a[6] - bflo(p2.w); o[7] = scale * a[7] - bfhi(p2.w);
            } else {
#pragma unroll
                for (int q = 0; q < 8; q++) o[q] = scale * a[q];
            }
            u32x4 pk;
            pk.x = packbf(o[0], o[1]); pk.y = packbf(o[2], o[3]);
            pk.z = packbf(o[4], o[5]); pk.w = packbf(o[6], o[7]);
            *(u32x4*)(outp + ob) = pk;
        }
        if (k < 15) {
            __syncthreads();   // drains vmcnt: stores resident in this XCD's L2
            if (t == 0) {
                int* c = &bar[320 + ((k - 1) * 8 + xcd) * 32];
                __hip_atomic_fetch_add(c, 1, __ATOMIC_RELAXED, __HIP_MEMORY_SCOPE_AGENT);
                while (__hip_atomic_load(c, __ATOMIC_RELAXED, __HIP_MEMORY_SCOPE_AGENT) < cnt)
                    __builtin_amdgcn_s_sleep(2);
            }
            __syncthreads();
        }
    }
}

// ------- GEMM1 (MFMA): panel-major A -> relu -> pool4 -> XS2 slice0 (panel-major) -------
__launch_bounds__(256)
__global__ void gemm1_mfma(const u16* __restrict__ XS1, const u16* __restrict__ B1p,
                           const float* __restrict__ b1, u16* __restrict__ XS2_0) {
    __shared__ u16 As[2][4096];     // [buf]: slice(2) x row(8) x col(256) row-major
    int t = threadIdx.x;
    int w = t >> 6, l = t & 63;
    int vr0 = blockIdx.x * 8;
    int nf = w & 1, vq = w >> 1;
    const size_t S1 = (size_t)V1q * 256;
    // stage element group: slice sl, row t>>5, col' (t&31)*8 -> panel (t&31)>>2, ofs (t&3)*8
    size_t sbase = ((size_t)((t & 31) >> 2) * V1q + vr0 + (t >> 5)) * 32 + (t & 3) * 8;

    f32x4 acc[4] = {};
    {
        short8* dst = (short8*)As[0];
        dst[t]       = *(const short8*)(XS1 + 0 * S1 + sbase);
        dst[256 + t] = *(const short8*)(XS1 + 1 * S1 + sbase);
    }
    __syncthreads();
    for (int s = 0; s < 8; s++) {
        int cur = s & 1;
        if (s < 7) {
            short8* dst = (short8*)As[cur ^ 1];
            dst[t]       = *(const short8*)(XS1 + (size_t)(2 * s + 2) * S1 + sbase);
            dst[256 + t] = *(const short8*)(XS1 + (size_t)(2 * s + 3) * S1 + sbase);
        }
        short8 bfrag = *(const short8*)(B1p + (((size_t)s * 2 + nf) * 64 + l) * 8);
        int abase = (l >> 5) * 2048 + (l & 31) * 8;
#pragma unroll
        for (int fm = 0; fm < 4; fm++) {
            int vl = vq * 4 + fm;
            short8 afrag = *(const short8*)&As[cur][abase + vl * 256];
            acc[fm] = __builtin_amdgcn_mfma_f32_16x16x32_bf16(afrag, bfrag, acc[fm], 0, 0, 0);
        }
        __syncthreads();
    }
    f32x4 m = acc[0];
#pragma unroll
    for (int fm = 1; fm < 4; fm++) {
#pragma unroll
        for (int i = 0; i < 4; i++) m[i] = fmaxf(m[i], acc[fm][i]);
    }
    int f1 = nf * 16 + (l & 15);
    float bias = b1[f1];
    int u_out = blockIdx.x * 2 + vq;
    int colbase = ((f1 >> 3) << 7) | (f1 & 7);
#pragma unroll
    for (int reg = 0; reg < 4; reg++) {
        int b = (l >> 4) * 4 + reg;
        int cc = colbase + b * 8;   // 0..511
        XS2_0[((size_t)(cc >> 6) * V2q + u_out) * 64 + (cc & 63)] =
            f2bf(fmaxf(m[reg] + bias, 0.f));
    }
}

// ------- GEMM2 (MFMA): panel-major A -> relu -> pool4 -> P2f fp32 -------
__launch_bounds__(256)
__global__ void gemm2_mfma(const u16* __restrict__ XS2, const u16* __restrict__ B2p,
                           const float* __restrict__ b2, float* __restrict__ P2f) {
    __shared__ u16 As[2][8192];          // [buf]: row(16) x col(512) row-major
    __shared__ float ylds[4 * 16 * 66];
    int t = threadIdx.x;
    int w = t >> 6, l = t & 63;
    int u0 = blockIdx.x * 16;
    const size_t S2 = (size_t)V2q * 512;

    f32x4 acc[4][4] = {};
    auto stage = [&](int buf, int k0) {
        short8* dst = (short8*)As[buf];
#pragma unroll
        for (int rr = 0; rr < 4; rr++) {
            int e = t * 4 + rr;          // entry: row e>>6, col (e&63)*8
            size_t sa = ((size_t)((e & 63) >> 3) * V2q + u0 + (e >> 6)) * 64 + (e & 7) * 8;
            dst[e] = *(const short8*)(XS2 + (size_t)k0 * S2 + sa);
        }
    };
    stage(0, 0);
    __syncthreads();
    for (int k = 0; k < 16; k++) {
        int cur = k & 1;
        if (k < 15) stage(cur ^ 1, k + 1);
        short8 bfrag[4];
#pragma unroll
        for (int nf = 0; nf < 4; nf++)
            bfrag[nf] = *(const short8*)(B2p + (((size_t)k * 4 + nf) * 64 + l) * 8);
#pragma unroll
        for (int fm = 0; fm < 4; fm++) {
            int ul = w * 4 + fm;
            short8 afrag = *(const short8*)&As[cur][ul * 512 + l * 8];
#pragma unroll
            for (int nf = 0; nf < 4; nf++)
                acc[fm][nf] = __builtin_amdgcn_mfma_f32_16x16x32_bf16(afrag, bfrag[nf], acc[fm][nf], 0, 0, 0);
        }
        __syncthreads();
    }
#pragma unroll
    for (int nf = 0; nf < 4; nf++) {
        int f2 = nf * 16 + (l & 15);
        float bias = b2[f2];
#pragma unroll
        for (int reg = 0; reg < 4; reg++) {
            int b = (l >> 4) * 4 + reg;
            float m = fmaxf(fmaxf(acc[0][nf][reg], acc[1][nf][reg]),
                            fmaxf(acc[2][nf][reg], acc[3][nf][reg]));
            ylds[(w * 16 + b) * 66 + f2] = fmaxf(m + bias, 0.f);
        }
    }
    __syncthreads();
    int ub = blockIdx.x * 4;
#pragma unroll
    for (int i = 0; i < 4; i++) {
        int p = t + i * 256;
        int b = p >> 6, f2 = p & 63;
        float4 v;
        v.x = ylds[(0 * 16 + b) * 66 + f2];
        v.y = ylds[(1 * 16 + b) * 66 + f2];
        v.z = ylds[(2 * 16 + b) * 66 + f2];
        v.w = ylds[(3 * 16 + b) * 66 + f2];
        *(float4*)&P2f[(size_t)(b * 64 + f2) * 1024 + ub] = v;
    }
}

// ---------------- FC ----------------
__global__ void fc_init(const float* __restrict__ b, float* __restrict__ out) {
    int i = blockIdx.x * 256 + threadIdx.x;   // 8192
    out[i] = b[i & 511];
}

__launch_bounds__(256)
__global__ void fc_mfma(const u16* __restrict__ Pp, const float* __restrict__ W,
                        float* __restrict__ out) {
    int t = threadIdx.x;
    int w = t >> 6, l = t & 63;
    int n0 = blockIdx.x * 16;
    int ks0 = blockIdx.y * 64 + w * 16;
    int o = n0 + (l & 15);
    const float* wp = W + (size_t)o * FCIN + (size_t)ks0 * 32 + (l >> 4) * 8;
    const u16*   ap = Pp + ((size_t)ks0 * 64 + l) * 8;
    f32x4 acc = {};
    for (int s = 0; s < 16; s++) {
        short8 afrag = *(const short8*)(ap + (size_t)s * 512);
        float4 w0 = *(const float4*)(wp + s * 32);
        float4 w1 = *(const float4*)(wp + s * 32 + 4);
        short8 bfrag;
        bfrag[0] = (short)f2bf(w0.x); bfrag[1] = (short)f2bf(w0.y);
        bfrag[2] = (short)f2bf(w0.z); bfrag[3] = (short)f2bf(w0.w);
        bfrag[4] = (short)f2bf(w1.x); bfrag[5] = (short)f2bf(w1.y);
        bfrag[6] = (short)f2bf(w1.z); bfrag[7] = (short)f2bf(w1.w);
        acc = __builtin_amdgcn_mfma_f32_16x16x32_bf16(afrag, bfrag, acc, 0, 0, 0);
    }
    __shared__ float red[4][256];
#pragma unroll
    for (int r = 0; r < 4; r++)
        red[w][((l >> 4) * 4 + r) * 16 + (l & 15)] = acc[r];
    __syncthreads();
    float s = red[0][t] + red[1][t] + red[2][t] + red[3][t];
    atomicAdd(&out[(t >> 4) * 512 + n0 + (t & 15)], s);
}

extern "C" void kernel_launch(void* const* d_in, const int* in_sizes, int n_in,
                              void* d_out, int out_size, void* d_ws, size_t ws_size,
                              hipStream_t stream) {
    const float* x       = (const float*)d_in[0];
    const int*   perm    = (const int*)d_in[1];
    const int*   l1_cols = (const int*)d_in[3];
    const float* l1_vals = (const float*)d_in[4];
    const int*   l2_cols = (const int*)d_in[6];
    const float* l2_vals = (const float*)d_in[7];
    const float* w1      = (const float*)d_in[8];
    const float* b1      = (const float*)d_in[9];
    const float* w2      = (const float*)d_in[10];
    const float* b2      = (const float*)d_in[11];
    const float* fcw     = (const float*)d_in[12];
    const float* fcb     = (const float*)d_in[13];
    float* out = (float*)d_out;

    char* wsb = (char*)d_ws;
    size_t off = 0;
    auto alloc = [&](size_t bytes) -> void* {
        void* p = wsb + off;
        off += (bytes + 255) & ~(size_t)255;
        return p;
    };
    float* mean_rstd = (float*)alloc(32 * 4);
    float* bnpart    = (float*)alloc(16 * 64 * 2 * 4);
    int*   iperm     = (int*)alloc((size_t)V1q * 4);
    int*   bar       = (int*)alloc((size_t)16384 * 4);
    u16*   idx1      = (u16*)alloc((size_t)V1q * 16 * 2);
    u16*   idx2      = (u16*)alloc((size_t)V2q * 16 * 2);
    u16*   valsb1    = (u16*)alloc((size_t)V1q * 16 * 2);
    u16*   valsb2    = (u16*)alloc((size_t)V2q * 16 * 2);
    u16*   B1p       = (u16*)alloc(8192 * 2);
    u16*   B2p       = (u16*)alloc(32768 * 2);
    u16*   XS1       = (u16*)alloc((size_t)Kq * V1q * 256 * 2);   // [k][8][V1][32]
    u16*   XS2       = (u16*)alloc((size_t)Kq * V2q * 512 * 2);   // [k][8][V2][64]
    float* P2f       = (float*)alloc((size_t)16 * FCIN * 4);
    u16*   Pp        = (u16*)alloc((size_t)16 * FCIN * 2);
    (void)ws_size; (void)in_sizes; (void)n_in; (void)out_size;

    zero_bar<<<64, 256, 0, stream>>>(bar);
    zero_ws<<<2048, 256, 0, stream>>>(XS1);
    bn_part<<<dim3(64, 16), 256, 0, stream>>>(x, bnpart);
    bn_final<<<1, 256, 0, stream>>>(bnpart, mean_rstd);
    build_iperm<<<V1q / 256, 256, 0, stream>>>(perm, iperm);
    build_idx16<<<V1q * 16 / 256, 256, 0, stream>>>(l1_cols, idx1, V1q * 16);
    build_idx16<<<V2q * 16 / 256, 256, 0, stream>>>(l2_cols, idx2, V2q * 16);
    pack_vals<<<V1q * 16 / 256, 256, 0, stream>>>(l1_vals, valsb1, V1q * 16);
    pack_vals<<<V2q * 16 / 256, 256, 0, stream>>>(l2_vals, valsb2, V2q * 16);
    norm_transpose_scatter<<<500, 256, 0, stream>>>(x, mean_rstd, iperm, XS1);
    pack_w1<<<32, 256, 0, stream>>>(w1, B1p);
    pack_w2<<<128, 256, 0, stream>>>(w2, B2p);

    // persistent panel-local Chebyshev chains
    cheb_panel<V1q, 5><<<1024, 256, 0, stream>>>(idx1, valsb1, XS1, bar);
    gemm1_mfma<<<V1q / 8, 256, 0, stream>>>(XS1, B1p, b1, XS2);
    cheb_panel<V2q, 6><<<1024, 256, 0, stream>>>(idx2, valsb2, XS2, bar + 8192);
    gemm2_mfma<<<V2q / 16, 256, 0, stream>>>(XS2, B2p, b2, P2f);

    // FC
    pack_p<<<512, 256, 0, stream>>>(P2f, Pp);
    fc_init<<<32, 256, 0, stream>>>(fcb, out);
    fc_mfma<<<dim3(32, 32), 256, 0, stream>>>(Pp, fcw, out);
}

// Round 14
// 453.627 us; speedup vs baseline: 1.7494x; 1.7494x over previous
//
#include <hip/hip_runtime.h>

#define VIN  16000
#define V1q  16384
#define V2q  4096
#define Kq   16
#define FCIN 65536

typedef unsigned short u16;
typedef unsigned int u32;
typedef __attribute__((ext_vector_type(8))) short short8;
typedef __attribute__((ext_vector_type(4))) float f32x4;
typedef __attribute__((ext_vector_type(2))) u32 u32x2;
typedef __attribute__((ext_vector_type(4))) u32 u32x4;

__device__ __forceinline__ float bf2f(u16 v) { return __uint_as_float((unsigned)v << 16); }
__device__ __forceinline__ float bflo(u32 u) { return __uint_as_float(u << 16); }
__device__ __forceinline__ float bfhi(u32 u) { return __uint_as_float(u & 0xffff0000u); }
__device__ __forceinline__ u16 f2bf(float f) {
    unsigned u = __float_as_uint(f);
    return (u16)((u + 0x7fffu + ((u >> 16) & 1u)) >> 16);
}
__device__ __forceinline__ u32 packbf(float a, float b) {
    return (u32)f2bf(a) | ((u32)f2bf(b) << 16);
}

// ---------------- workspace zero (X0 pad rows) ----------------
__global__ void zero_ws(u16* __restrict__ X0) {
    size_t idx = (size_t)blockIdx.x * 256 + threadIdx.x;   // 2048*256 = 524288
    float4 z = {0.f, 0.f, 0.f, 0.f};
    *(float4*)(X0 + idx * 8) = z;
}

// ---------------- BatchNorm stats (two stage) ----------------
__global__ void bn_part(const float* __restrict__ x, float* __restrict__ part) {
    int c  = blockIdx.y;
    int bx = blockIdx.x;           // 0..63
    int b  = bx >> 2;
    int vc = bx & 3;
    const float* p = x + (size_t)(b * 16 + c) * VIN + vc * 4000;
    float s = 0.f, s2 = 0.f;
    for (int v = threadIdx.x; v < 4000; v += 256) {
        float val = p[v];
        s += val; s2 += val * val;
    }
    for (int o = 32; o; o >>= 1) { s += __shfl_down(s, o); s2 += __shfl_down(s2, o); }
    __shared__ float ls[4], ls2[4];
    int wid = threadIdx.x >> 6;
    if ((threadIdx.x & 63) == 0) { ls[wid] = s; ls2[wid] = s2; }
    __syncthreads();
    if (threadIdx.x == 0) {
        s = ls[0] + ls[1] + ls[2] + ls[3];
        s2 = ls2[0] + ls2[1] + ls2[2] + ls2[3];
        part[(c * 64 + bx) * 2]     = s;
        part[(c * 64 + bx) * 2 + 1] = s2;
    }
}

__global__ void bn_final(const float* __restrict__ part, float* __restrict__ mean_rstd) {
    int t = threadIdx.x;
    int c = t >> 4, j = t & 15;
    float s = 0.f, s2 = 0.f;
    for (int i = 0; i < 4; i++) {
        s  += part[(c * 64 + j * 4 + i) * 2];
        s2 += part[(c * 64 + j * 4 + i) * 2 + 1];
    }
    for (int o = 8; o; o >>= 1) { s += __shfl_down(s, o, 16); s2 += __shfl_down(s2, o, 16); }
    if (j == 0) {
        float m  = s / 256000.f;
        float var = s2 / 256000.f - m * m;
        mean_rstd[c]      = m;
        mean_rstd[16 + c] = rsqrtf(var + 1e-5f);
    }
}

// ---------------- inverse permutation ----------------
__global__ void build_iperm(const int* __restrict__ perm, int* __restrict__ iperm) {
    int v = blockIdx.x * 256 + threadIdx.x;
    if (v < V1q) iperm[perm[v]] = v;
}

// ------- normalize + transpose + permute scatter, bf16, fragment column order -------
__global__ void norm_transpose_scatter(const float* __restrict__ x,
                                       const float* __restrict__ mean_rstd,
                                       const int* __restrict__ iperm,
                                       u16* __restrict__ X0) {
    __shared__ u16 tile[256][33];
    int u0 = blockIdx.x * 32;
    int t  = threadIdx.x;
    int jj = t & 31, half = t >> 5;
    for (int rr = 0; rr < 32; rr++) {
        int s = rr * 8 + half;           // source row = b*16 + c
        int c = s & 15, b = s >> 4;
        float val = x[(size_t)s * VIN + u0 + jj];
        val = (val - mean_rstd[c]) * mean_rstd[16 + c];
        int d = ((c >> 3) << 7) | (b << 3) | (c & 7);
        tile[d][jj] = f2bf(val);
    }
    __syncthreads();
    for (int j = 0; j < 32; j++) {
        int tv = iperm[u0 + j];
        X0[(size_t)tv * 256 + t] = tile[t][j];
    }
}

// ---------------- weight packing into MFMA B-fragment order ----------------
__global__ void pack_w1(const float* __restrict__ w1, u16* __restrict__ B1p) {
    int i = blockIdx.x * 256 + threadIdx.x;   // 8192
    int j = i & 7, l = (i >> 3) & 63, nf = (i >> 9) & 1, s = i >> 10;
    int q = l >> 4;
    int k = s * 2 + (q >> 1);
    int c = (q & 1) * 8 + j;
    int f = nf * 16 + (l & 15);
    B1p[i] = f2bf(w1[f * 256 + c * 16 + k]);
}
__global__ void pack_w2(const float* __restrict__ w2, u16* __restrict__ B2p) {
    int i = blockIdx.x * 256 + threadIdx.x;   // 32768
    int j = i & 7, l = (i >> 3) & 63, nf = (i >> 9) & 3, k = i >> 11;
    int f1 = (l >> 4) * 8 + j;
    int f2 = nf * 16 + (l & 15);
    B2p[i] = f2bf(w2[f2 * 512 + f1 * 16 + k]);
}

// ------- pack P2f fp32 -> bf16 A-fragment order for FC MFMA -------
__global__ void pack_p(const float* __restrict__ P2f, u16* __restrict__ Pp) {
    int i = blockIdx.x * 256 + threadIdx.x;   // 131072
    int l = i & 63, ks = i >> 6;
    int b = l & 15, q = l >> 4;
    const float* src = P2f + (size_t)b * FCIN + ks * 32 + q * 8;
    float4 a0 = *(const float4*)(src);
    float4 a1 = *(const float4*)(src + 4);
    short8 v;
    v[0] = (short)f2bf(a0.x); v[1] = (short)f2bf(a0.y);
    v[2] = (short)f2bf(a0.z); v[3] = (short)f2bf(a0.w);
    v[4] = (short)f2bf(a1.x); v[5] = (short)f2bf(a1.y);
    v[6] = (short)f2bf(a1.z); v[7] = (short)f2bf(a1.w);
    *(short8*)(Pp + (size_t)i * 8) = v;
}

// ---------------- Chebyshev SpMM: 1 row/wave, all 16 gathers in flight ----------------
// WLOG=8: 256-col rows, lane holds 4 cols (u32x2). WLOG=9: 512-col, 8 cols (u32x4).
template<int WLOG>
__launch_bounds__(256)
__global__ void spmm_mlp(const u16* __restrict__ prev, const u16* __restrict__ prev2,
                         u16* __restrict__ out,
                         const int* __restrict__ cols, const float* __restrict__ vals,
                         float scale, int sub) {
    int lane = threadIdx.x & 63;
    int r = __builtin_amdgcn_readfirstlane(blockIdx.x * 4 + (threadIdx.x >> 6));
    // wave-uniform idx/val loads (SGPR)
    const int4*   cp = (const int4*)(cols + r * 16);
    const float4* vp = (const float4*)(vals + r * 16);
    int4 c0 = cp[0], c1 = cp[1], c2 = cp[2], c3 = cp[3];
    float4 v0 = vp[0], v1 = vp[1], v2 = vp[2], v3 = vp[3];
    int cidx[16] = {c0.x, c0.y, c0.z, c0.w, c1.x, c1.y, c1.z, c1.w,
                    c2.x, c2.y, c2.z, c2.w, c3.x, c3.y, c3.z, c3.w};
    float vv[16] = {v0.x, v0.y, v0.z, v0.w, v1.x, v1.y, v1.z, v1.w,
                    v2.x, v2.y, v2.z, v2.w, v3.x, v3.y, v3.z, v3.w};
#pragma unroll
    for (int j = 0; j < 16; j++)
        cidx[j] = __builtin_amdgcn_readfirstlane(cidx[j]);

    if constexpr (WLOG == 8) {
        u32x2 g[16];
#pragma unroll
        for (int j = 0; j < 16; j++)
            g[j] = *(const u32x2*)(prev + ((size_t)cidx[j] << 8) + lane * 4);
        float acc[4] = {0.f, 0.f, 0.f, 0.f};
#pragma unroll
        for (int j = 0; j < 16; j++) {
            float v = vv[j];
            acc[0] += v * bflo(g[j].x); acc[1] += v * bfhi(g[j].x);
            acc[2] += v * bflo(g[j].y); acc[3] += v * bfhi(g[j].y);
        }
        size_t ob = ((size_t)r << 8) + lane * 4;
        float o[4];
        if (sub) {
            u32x2 p2 = __builtin_nontemporal_load((const u32x2*)(prev2 + ob));
            o[0] = scale * acc[0] - bflo(p2.x); o[1] = scale * acc[1] - bfhi(p2.x);
            o[2] = scale * acc[2] - bflo(p2.y); o[3] = scale * acc[3] - bfhi(p2.y);
        } else {
#pragma unroll
            for (int i = 0; i < 4; i++) o[i] = scale * acc[i];
        }
        u32x2 pk; pk.x = packbf(o[0], o[1]); pk.y = packbf(o[2], o[3]);
        *(u32x2*)(out + ob) = pk;
    } else {
        u32x4 g[16];
#pragma unroll
        for (int j = 0; j < 16; j++)
            g[j] = *(const u32x4*)(prev + ((size_t)cidx[j] << 9) + lane * 8);
        float acc[8] = {0.f, 0.f, 0.f, 0.f, 0.f, 0.f, 0.f, 0.f};
#pragma unroll
        for (int j = 0; j < 16; j++) {
            float v = vv[j];
            acc[0] += v * bflo(g[j].x); acc[1] += v * bfhi(g[j].x);
            acc[2] += v * bflo(g[j].y); acc[3] += v * bfhi(g[j].y);
            acc[4] += v * bflo(g[j].z); acc[5] += v * bfhi(g[j].z);
            acc[6] += v * bflo(g[j].w); acc[7] += v * bfhi(g[j].w);
        }
        size_t ob = ((size_t)r << 9) + lane * 8;
        float o[8];
        if (sub) {
            u32x4 p2 = __builtin_nontemporal_load((const u32x4*)(prev2 + ob));
            o[0] = scale * acc[0] - bflo(p2.x); o[1] = scale * acc[1] - bfhi(p2.x);
            o[2] = scale * acc[2] - bflo(p2.y); o[3] = scale * acc[3] - bfhi(p2.y);
            o[4] = scale * acc[4] - bflo(p2.z); o[5] = scale * acc[5] - bfhi(p2.z);
            o[6] = scale * acc[6] - bflo(p2.w); o[7] = scale * acc[7] - bfhi(p2.w);
        } else {
#pragma unroll
            for (int i = 0; i < 8; i++) o[i] = scale * acc[i];
        }
        u32x4 pk;
        pk.x = packbf(o[0], o[1]); pk.y = packbf(o[2], o[3]);
        pk.z = packbf(o[4], o[5]); pk.w = packbf(o[6], o[7]);
        *(u32x4*)(out + ob) = pk;
    }
}

// ------- GEMM1 (MFMA): (v,b)x(c,k) @ w1 -> relu -> pool4 over v -> XS2 slice0 -------
__launch_bounds__(256)
__global__ void gemm1_mfma(const u16* __restrict__ XS1, const u16* __restrict__ B1p,
                           const float* __restrict__ b1, u16* __restrict__ XS2_0) {
    __shared__ u16 As[2][4096];     // [buf]: slice(2) x row(8) x col(256)
    int t = threadIdx.x;
    int w = t >> 6, l = t & 63;
    int v0 = blockIdx.x * 8;
    int nf = w & 1, vq = w >> 1;

    f32x4 acc[4] = {};
    {
        const short8* s0 = (const short8*)(XS1 + (size_t)(0 * V1q + v0) * 256);
        const short8* s1 = (const short8*)(XS1 + (size_t)(1 * V1q + v0) * 256);
        short8* dst = (short8*)As[0];
        dst[t] = s0[t]; dst[256 + t] = s1[t];
    }
    __syncthreads();
    for (int s = 0; s < 8; s++) {
        int cur = s & 1;
        if (s < 7) {
            const short8* s0 = (const short8*)(XS1 + (size_t)((2 * s + 2) * V1q + v0) * 256);
            const short8* s1 = (const short8*)(XS1 + (size_t)((2 * s + 3) * V1q + v0) * 256);
            short8* dst = (short8*)As[cur ^ 1];
            dst[t] = s0[t]; dst[256 + t] = s1[t];
        }
        short8 bfrag = *(const short8*)(B1p + (((size_t)s * 2 + nf) * 64 + l) * 8);
        int abase = (l >> 5) * 2048 + (l & 31) * 8;
#pragma unroll
        for (int fm = 0; fm < 4; fm++) {
            int vl = vq * 4 + fm;
            short8 afrag = *(const short8*)&As[cur][abase + vl * 256];
            acc[fm] = __builtin_amdgcn_mfma_f32_16x16x32_bf16(afrag, bfrag, acc[fm], 0, 0, 0);
        }
        __syncthreads();
    }
    f32x4 m = acc[0];
#pragma unroll
    for (int fm = 1; fm < 4; fm++) {
#pragma unroll
        for (int i = 0; i < 4; i++) m[i] = fmaxf(m[i], acc[fm][i]);
    }
    int f1 = nf * 16 + (l & 15);
    float bias = b1[f1];
    int u_out = blockIdx.x * 2 + vq;
    u16* orow = XS2_0 + (size_t)u_out * 512;
    int colbase = ((f1 >> 3) << 7) | (f1 & 7);
#pragma unroll
    for (int reg = 0; reg < 4; reg++) {
        int b = (l >> 4) * 4 + reg;
        orow[colbase + b * 8] = f2bf(fmaxf(m[reg] + bias, 0.f));
    }
}

// ------- GEMM2 (MFMA): (u,b)x(f1,k) @ w2 -> relu -> pool4 over u -> P2f fp32 -------
__launch_bounds__(256)
__global__ void gemm2_mfma(const u16* __restrict__ XS2, const u16* __restrict__ B2p,
                           const float* __restrict__ b2, float* __restrict__ P2f) {
    __shared__ u16 As[2][8192];          // [buf]: row(16) x col(512)
    __shared__ float ylds[4 * 16 * 66];  // [w][b][f2] padded
    int t = threadIdx.x;
    int w = t >> 6, l = t & 63;
    int u0 = blockIdx.x * 16;

    f32x4 acc[4][4] = {};
    {
        const short8* src = (const short8*)(XS2 + (size_t)(0 * V2q + u0) * 512);
        short8* dst = (short8*)As[0];
#pragma unroll
        for (int r = 0; r < 4; r++) dst[t * 4 + r] = src[t * 4 + r];
    }
    __syncthreads();
    for (int k = 0; k < 16; k++) {
        int cur = k & 1;
        if (k < 15) {
            const short8* src = (const short8*)(XS2 + (size_t)((k + 1) * V2q + u0) * 512);
            short8* dst = (short8*)As[cur ^ 1];
#pragma unroll
            for (int r = 0; r < 4; r++) dst[t * 4 + r] = src[t * 4 + r];
        }
        short8 bfrag[4];
#pragma unroll
        for (int nf = 0; nf < 4; nf++)
            bfrag[nf] = *(const short8*)(B2p + (((size_t)k * 4 + nf) * 64 + l) * 8);
#pragma unroll
        for (int fm = 0; fm < 4; fm++) {
            int ul = w * 4 + fm;
            short8 afrag = *(const short8*)&As[cur][ul * 512 + l * 8];
#pragma unroll
            for (int nf = 0; nf < 4; nf++)
                acc[fm][nf] = __builtin_amdgcn_mfma_f32_16x16x32_bf16(afrag, bfrag[nf], acc[fm][nf], 0, 0, 0);
        }
        __syncthreads();
    }
#pragma unroll
    for (int nf = 0; nf < 4; nf++) {
        int f2 = nf * 16 + (l & 15);
        float bias = b2[f2];
#pragma unroll
        for (int reg = 0; reg < 4; reg++) {
            int b = (l >> 4) * 4 + reg;
            float m = fmaxf(fmaxf(acc[0][nf][reg], acc[1][nf][reg]),
                            fmaxf(acc[2][nf][reg], acc[3][nf][reg]));
            ylds[(w * 16 + b) * 66 + f2] = fmaxf(m + bias, 0.f);
        }
    }
    __syncthreads();
    int ub = blockIdx.x * 4;
#pragma unroll
    for (int i = 0; i < 4; i++) {
        int p = t + i * 256;
        int b = p >> 6, f2 = p & 63;
        float4 v;
        v.x = ylds[(0 * 16 + b) * 66 + f2];
        v.y = ylds[(1 * 16 + b) * 66 + f2];
        v.z = ylds[(2 * 16 + b) * 66 + f2];
        v.w = ylds[(3 * 16 + b) * 66 + f2];
        *(float4*)&P2f[(size_t)(b * 64 + f2) * 1024 + ub] = v;
    }
}

// ---------------- FC ----------------
__global__ void fc_init(const float* __restrict__ b, float* __restrict__ out) {
    int i = blockIdx.x * 256 + threadIdx.x;   // 8192
    out[i] = b[i & 511];
}

__launch_bounds__(256)
__global__ void fc_mfma(const u16* __restrict__ Pp, const float* __restrict__ W,
                        float* __restrict__ out) {
    int t = threadIdx.x;
    int w = t >> 6, l = t & 63;
    int n0 = blockIdx.x * 16;
    int ks0 = blockIdx.y * 64 + w * 16;
    int o = n0 + (l & 15);
    const float* wp = W + (size_t)o * FCIN + (size_t)ks0 * 32 + (l >> 4) * 8;
    const u16*   ap = Pp + ((size_t)ks0 * 64 + l) * 8;
    f32x4 acc = {};
    for (int s = 0; s < 16; s++) {
        short8 afrag = *(const short8*)(ap + (size_t)s * 512);
        float4 w0 = *(const float4*)(wp + s * 32);
        float4 w1 = *(const float4*)(wp + s * 32 + 4);
        short8 bfrag;
        bfrag[0] = (short)f2bf(w0.x); bfrag[1] = (short)f2bf(w0.y);
        bfrag[2] = (short)f2bf(w0.z); bfrag[3] = (short)f2bf(w0.w);
        bfrag[4] = (short)f2bf(w1.x); bfrag[5] = (short)f2bf(w1.y);
        bfrag[6] = (short)f2bf(w1.z); bfrag[7] = (short)f2bf(w1.w);
        acc = __builtin_amdgcn_mfma_f32_16x16x32_bf16(afrag, bfrag, acc, 0, 0, 0);
    }
    __shared__ float red[4][256];
#pragma unroll
    for (int r = 0; r < 4; r++)
        red[w][((l >> 4) * 4 + r) * 16 + (l & 15)] = acc[r];
    __syncthreads();
    float s = red[0][t] + red[1][t] + red[2][t] + red[3][t];
    atomicAdd(&out[(t >> 4) * 512 + n0 + (t & 15)], s);
}

extern "C" void kernel_launch(void* const* d_in, const int* in_sizes, int n_in,
                              void* d_out, int out_size, void* d_ws, size_t ws_size,
                              hipStream_t stream) {
    const float* x       = (const float*)d_in[0];
    const int*   perm    = (const int*)d_in[1];
    const int*   l1_cols = (const int*)d_in[3];
    const float* l1_vals = (const float*)d_in[4];
    const int*   l2_cols = (const int*)d_in[6];
    const float* l2_vals = (const float*)d_in[7];
    const float* w1      = (const float*)d_in[8];
    const float* b1      = (const float*)d_in[9];
    const float* w2      = (const float*)d_in[10];
    const float* b2      = (const float*)d_in[11];
    const float* fcw     = (const float*)d_in[12];
    const float* fcb     = (const float*)d_in[13];
    float* out = (float*)d_out;

    char* wsb = (char*)d_ws;
    size_t off = 0;
    auto alloc = [&](size_t bytes) -> void* {
        void* p = wsb + off;
        off += (bytes + 255) & ~(size_t)255;
        return p;
    };
    float* mean_rstd = (float*)alloc(32 * 4);
    float* bnpart    = (float*)alloc(16 * 64 * 2 * 4);
    int*   iperm     = (int*)alloc((size_t)V1q * 4);
    u16*   B1p       = (u16*)alloc(8192 * 2);
    u16*   B2p       = (u16*)alloc(32768 * 2);
    u16*   XS1       = (u16*)alloc((size_t)Kq * V1q * 256 * 2);
    u16*   XS2       = (u16*)alloc((size_t)Kq * V2q * 512 * 2);
    float* P2f       = (float*)alloc((size_t)16 * FCIN * 4);
    u16*   Pp        = (u16*)alloc((size_t)16 * FCIN * 2);
    (void)ws_size; (void)in_sizes; (void)n_in; (void)out_size;

    const size_t S1 = (size_t)V1q * 256;
    const size_t S2 = (size_t)V2q * 512;

    zero_ws<<<2048, 256, 0, stream>>>(XS1);
    bn_part<<<dim3(64, 16), 256, 0, stream>>>(x, bnpart);
    bn_final<<<1, 256, 0, stream>>>(bnpart, mean_rstd);
    build_iperm<<<V1q / 256, 256, 0, stream>>>(perm, iperm);
    norm_transpose_scatter<<<500, 256, 0, stream>>>(x, mean_rstd, iperm, XS1);
    pack_w1<<<32, 256, 0, stream>>>(w1, B1p);
    pack_w2<<<128, 256, 0, stream>>>(w2, B2p);

    // Chebyshev levels, conv1: 1 row/wave, 16 gathers in flight
    spmm_mlp<8><<<V1q / 4, 256, 0, stream>>>(XS1, XS1, XS1 + S1, l1_cols, l1_vals, 1.f, 0);
    for (int k = 2; k < Kq; k++)
        spmm_mlp<8><<<V1q / 4, 256, 0, stream>>>(XS1 + (size_t)(k - 1) * S1, XS1 + (size_t)(k - 2) * S1,
                                                 XS1 + (size_t)k * S1, l1_cols, l1_vals, 2.f, 1);
    gemm1_mfma<<<V1q / 8, 256, 0, stream>>>(XS1, B1p, b1, XS2);

    // Chebyshev levels, conv2
    spmm_mlp<9><<<V2q / 4, 256, 0, stream>>>(XS2, XS2, XS2 + S2, l2_cols, l2_vals, 1.f, 0);
    for (int k = 2; k < Kq; k++)
        spmm_mlp<9><<<V2q / 4, 256, 0, stream>>>(XS2 + (size_t)(k - 1) * S2, XS2 + (size_t)(k - 2) * S2,
                                                 XS2 + (size_t)k * S2, l2_cols, l2_vals, 2.f, 1);
    gemm2_mfma<<<V2q / 16, 256, 0, stream>>>(XS2, B2p, b2, P2f);

    // FC
    pack_p<<<512, 256, 0, stream>>>(P2f, Pp);
    fc_init<<<32, 256, 0, stream>>>(fcb, out);
    fc_mfma<<<dim3(32, 32), 256, 0, stream>>>(Pp, fcw, out);
}